// Round 5
// baseline (1853.626 us; speedup 1.0000x reference)
//
#include <hip/hip_runtime.h>
#include <cstddef>
#include <cstdint>

// B=64, T_CAP=32, V=32000, E=D=1024, gates=4096, t_dec=31.
// d_out: preds[64*31*32000] ++ decode_lengths[64] ++ sort_ind[64]  (float dtype detected at runtime).
// Runtime dtype dispatch: flags[0]=1 if floats are fp32 (else bf16), flags[1]=1 if ints are int64.
// Scratch layout in d_out's preds region (dead until k_gemm_fc overwrites it; region >= 121MB):
//   gatesx fp32 [0,32MB) ++ Xbuf bf16 [32,36MB) ++ Whh16 bf16 [36,44.4MB) ++ Wih16 bf16 [44.4,52.8MB)
// d_ws: flags(+bar)+wsI+Hbuf (~4.5MB) ++ (optional, if ws_size>=74MB) fcW16 bf16 @ +8MB (65.5MB).
#define PRED_N 63488000

typedef unsigned short u16;
typedef unsigned long long u64;
typedef __attribute__((ext_vector_type(8))) unsigned short us8;
typedef __attribute__((ext_vector_type(4))) float f32x4;
typedef __attribute__((ext_vector_type(8))) __bf16 bf16x8;

__device__ __forceinline__ float bf2f(u16 h){
  unsigned u = ((unsigned)h) << 16;
  return __builtin_bit_cast(float, u);
}
__device__ __forceinline__ u16 f2bf(float f){
  unsigned u = __builtin_bit_cast(unsigned, f);
  u += 0x7FFFu + ((u >> 16) & 1u);
  return (u16)(u >> 16);
}
__device__ __forceinline__ float sigf(float x){ return 1.f/(1.f + __expf(-x)); }
__device__ __forceinline__ float tanhf_(float x){ return 1.f - 2.f/(__expf(2.f*x) + 1.f); }

__device__ __forceinline__ f32x4 mfma16(us8 a, us8 b, f32x4 c){
  return __builtin_amdgcn_mfma_f32_16x16x32_bf16(
      __builtin_bit_cast(bf16x8, a), __builtin_bit_cast(bf16x8, b), c, 0, 0, 0);
}
__device__ __forceinline__ u64 pack4bf(const float* h){
  return (u64)f2bf(h[0]) | ((u64)f2bf(h[1]) << 16)
       | ((u64)f2bf(h[2]) << 32) | ((u64)f2bf(h[3]) << 48);
}
__device__ __forceinline__ us8 pack8(float4 a, float4 b){
  us8 r;
  r[0]=f2bf(a.x); r[1]=f2bf(a.y); r[2]=f2bf(a.z); r[3]=f2bf(a.w);
  r[4]=f2bf(b.x); r[5]=f2bf(b.y); r[6]=f2bf(b.z); r[7]=f2bf(b.w);
  return r;
}
// scalar read of a float array of unknown dtype
__device__ __forceinline__ float ldf(const void* p, int f32, int i){
  return f32 ? ((const float*)p)[i] : bf2f(((const u16*)p)[i]);
}
__device__ __forceinline__ int ldi(const int* p, int i64, int i){
  return i64 ? p[2*i] : p[i];   // little-endian low word; values < 2^31
}
// uncached (L1/L2-bypassing, L3-coherent) H exchange for the persistent RNN kernel
__device__ __forceinline__ void stH(u16* p, u64 v){
  __hip_atomic_store((u64*)p, v, __ATOMIC_RELAXED, __HIP_MEMORY_SCOPE_AGENT);
}
__device__ __forceinline__ us8 ldH8(const u16* p){
  union { u64 q[2]; us8 v; } u;
  u.q[0] = __hip_atomic_load((const u64*)p,       __ATOMIC_RELAXED, __HIP_MEMORY_SCOPE_AGENT);
  u.q[1] = __hip_atomic_load((const u64*)(p + 4), __ATOMIC_RELAXED, __HIP_MEMORY_SCOPE_AGENT);
  return u.v;
}

// ---------------- K0: dtype detector (+ barrier reset for this run) ----------------
__global__ void k_detect(const unsigned* __restrict__ embw, const int* __restrict__ lenw,
                         int* __restrict__ flags){
  if(threadIdx.x == 0){
    int hits = 0;
    for(int i = 0; i < 16; ++i){
      unsigned w = embw[i];
      int elo = (w >> 7) & 0xFF, ehi = (w >> 23) & 0xFF;
      hits += (elo >= 112 && elo <= 133) && (ehi >= 112 && ehi <= 133);
    }
    flags[0] = (hits >= 12) ? 0 : 1;        // 1 = fp32 floats
    int orv = 0;
    for(int i = 0; i < 4; ++i) orv |= lenw[2*i + 1];
    flags[1] = (orv == 0) ? 1 : 0;          // 1 = int64 ints
    // reset grid-barrier counter (uncached store so k_rnn4's uncached RMWs see it)
    __hip_atomic_store((unsigned*)(flags + 48), 0u, __ATOMIC_RELAXED, __HIP_MEMORY_SCOPE_AGENT);
  }
}

// ---------------- K1: stable descending sort + tail outputs ----------------
__global__ void k_setup(const int* __restrict__ lens, int* __restrict__ wsI,
                        const int* __restrict__ flags, void* __restrict__ out){
  const int i = threadIdx.x;                // 64 threads
  const int f32 = flags[0], i64 = flags[1];
  const int li = ldi(lens, i64, i);
  int rank = 0;
  for(int j = 0; j < 64; ++j){
    const int lj = ldi(lens, i64, j);
    rank += (lj > li) || (lj == li && j < i);   // stable descending
  }
  wsI[rank]      = i;                       // sort_ind
  wsI[64 + rank] = li - 1;                  // decode_lengths (sorted order)
  if(f32){
    ((float*)out)[PRED_N + rank]      = (float)(li - 1);
    ((float*)out)[PRED_N + 64 + rank] = (float)i;
  } else {
    ((u16*)out)[PRED_N + rank]      = f2bf((float)(li - 1));
    ((u16*)out)[PRED_N + 64 + rank] = f2bf((float)i);
  }
}

// ---------------- K1b: weight convert (fp32 -> bf16 RNE, or copy if already bf16) ----------------
__global__ void __launch_bounds__(256) k_conv16(const void* __restrict__ W,
    const int* __restrict__ flags, u16* __restrict__ dst, int n8){
  const int f32 = flags[0];
  const int stride = gridDim.x * 256;
  for(int i = blockIdx.x * 256 + threadIdx.x; i < n8; i += stride){
    if(f32){
      const float4* s = (const float4*)W + 2 * (size_t)i;
      ((us8*)dst)[i] = pack8(s[0], s[1]);
    } else {
      ((uint4*)dst)[i] = ((const uint4*)W)[i];
    }
  }
}

// ---------------- K2: build X (2048x1024 bf16), row t*64+b ----------------
__global__ void __launch_bounds__(256) k_gather(const void* __restrict__ enc,
    const int* __restrict__ caps, const void* __restrict__ emb,
    const int* __restrict__ wsI, const int* __restrict__ flags, u16* __restrict__ X){
  const int r = blockIdx.x, t = r >> 6, b = r & 63;
  const int f32 = flags[0], i64 = flags[1];
  const int sb = wsI[b];
  const size_t rowoff = (t == 0) ? (size_t)sb * 1024
                                 : (size_t)ldi(caps, i64, sb * 32 + (t - 1)) * 1024;
  const void* base = (t == 0) ? enc : emb;
  u16* dst = X + (size_t)r * 1024;
  if(f32){
    const float4* src = (const float4*)((const float*)base + rowoff);
    float4 v = src[threadIdx.x];            // 4 floats per thread
    u64 w = (u64)f2bf(v.x) | ((u64)f2bf(v.y) << 16)
          | ((u64)f2bf(v.z) << 32) | ((u64)f2bf(v.w) << 48);
    ((u64*)dst)[threadIdx.x] = w;
  } else {
    const uint2* src = (const uint2*)((const u16*)base + rowoff);
    ((uint2*)dst)[threadIdx.x] = src[threadIdx.x];  // 4 bf16 per thread
  }
}

// ---------------- 128x128 K=1024 MFMA mainloop; XOR-swizzled LDS (T2) ----------------
__device__ __forceinline__ void gemm_main(const u16* __restrict__ A, const void* __restrict__ Bv,
    int bF32, int arowmax, u16* As, u16* Bs, f32x4 (&acc)[4][4]){
  const int tid = threadIdx.x, wave = tid >> 6, lane = tid & 63;
  const int mq = (wave >> 1) * 64, nq = (wave & 1) * 64;
  const int l15 = lane & 15, lq = lane >> 4;
  const int r0 = lane >> 2, c0 = (lane & 3) * 8;     // within a 16x32 chunk
  const int sww = ((r0 & 7) << 3);                   // write-side swizzle
  const int swr = ((l15 & 7) << 3);                  // read-side swizzle
  const u16* Bb = (const u16*)Bv; const float* Bf = (const float*)Bv;
  for(int k0 = 0; k0 < 1024; k0 += 32){
    us8 av[2], bv[2];
#pragma unroll
    for(int c2 = 0; c2 < 2; ++c2){
      const int chunk = wave * 2 + c2;               // 8 chunks of 16 rows
      int ar = chunk * 16 + r0; if(ar > arowmax) ar = arowmax;
      av[c2] = *(const us8*)(A + (size_t)ar * 1024 + k0 + c0);
      const size_t bo = (size_t)(chunk * 16 + r0) * 1024 + k0 + c0;
      if(bF32){
        const float* p = Bf + bo;
        bv[c2] = pack8(*(const float4*)p, *(const float4*)(p + 4));
      } else {
        bv[c2] = *(const us8*)(Bb + bo);
      }
    }
    __syncthreads();   // previous iteration's LDS reads complete
#pragma unroll
    for(int c2 = 0; c2 < 2; ++c2){
      const int chunk = wave * 2 + c2;
      *(us8*)&As[(chunk * 512 + r0 * 32 + c0) ^ sww] = av[c2];
      *(us8*)&Bs[(chunk * 512 + r0 * 32 + c0) ^ sww] = bv[c2];
    }
    __syncthreads();
    us8 af[4], bfv[4];
#pragma unroll
    for(int i = 0; i < 4; ++i){
      af[i]  = *(const us8*)&As[((mq + i * 16 + l15) * 32 + lq * 8) ^ swr];
      bfv[i] = *(const us8*)&Bs[((nq + i * 16 + l15) * 32 + lq * 8) ^ swr];
    }
#pragma unroll
    for(int i = 0; i < 4; ++i)
#pragma unroll
      for(int j = 0; j < 4; ++j)
        acc[i][j] = mfma16(af[i], bfv[j], acc[i][j]);
  }
}

// ---------------- K3: gates_x = X @ W_ih^T + (b_ih + b_hh), fp32 ----------------
__global__ void __launch_bounds__(256) k_gemm_gates(const u16* __restrict__ X,
    const u16* __restrict__ Wih16, const void* __restrict__ bih, const void* __restrict__ bhh,
    const int* __restrict__ flags, float* __restrict__ gatesx){
  __shared__ u16 As[4096], Bs[4096];
  const int tid = threadIdx.x, wave = tid >> 6, lane = tid & 63;
  const int bm = blockIdx.x, bn = blockIdx.y;
  const int mq = (wave >> 1) * 64, nq = (wave & 1) * 64;
  const int l15 = lane & 15, lq = lane >> 4;
  const int f32 = flags[0];
  f32x4 acc[4][4] = {};
  gemm_main(X + (size_t)bm * 128 * 1024, Wih16 + (size_t)bn * 128 * 1024, 0, 127, As, Bs, acc);
  const int rowb = bm * 128 + mq, colb = bn * 128 + nq;
#pragma unroll
  for(int j = 0; j < 4; ++j){
    const int col = colb + j * 16 + l15;
    const float bias = ldf(bih, f32, col) + ldf(bhh, f32, col);
#pragma unroll
    for(int i = 0; i < 4; ++i)
#pragma unroll
      for(int v = 0; v < 4; ++v){
        const int row = rowb + i * 16 + lq * 4 + v;
        gatesx[(size_t)row * 4096 + col] = acc[i][j][v] + bias;
      }
  }
}

// ---------------- hardened lightweight grid barrier ----------------
// Data exchange (Hbuf) is uncached agent-scope; this barrier provides execution
// ordering plus belt-and-braces fences: all-thread agent fence before the add,
// release add / acquire exit, full compiler memory barriers on both sides.
__device__ __forceinline__ void gbar(unsigned* bar, unsigned tgt, int tid){
  asm volatile("" ::: "memory");
  __syncthreads();
  __threadfence();                       // agent-scope fence: every wave drains/orders
  if(tid == 0){
    __hip_atomic_fetch_add(bar, 1u, __ATOMIC_RELEASE, __HIP_MEMORY_SCOPE_AGENT);
    while(__hip_atomic_load(bar, __ATOMIC_RELAXED, __HIP_MEMORY_SCOPE_AGENT) < tgt)
      __builtin_amdgcn_s_sleep(1);
    (void)__hip_atomic_load(bar, __ATOMIC_ACQUIRE, __HIP_MEMORY_SCOPE_AGENT);
  }
  __syncthreads();
  __builtin_amdgcn_sched_barrier(0);
  asm volatile("" ::: "memory");
}

// ---------------- K5: persistent RNN — ROUND-2-VERIFIED GEOMETRY, new mechanics ----
// 64 blocks x 256 threads. Block owns dims [blk*16, blk*16+16); wave w = gate w.
// Each wave computes full K=1024 for its gate (exact r2 index formulas, which passed
// the harness). Only the sync (inline gbar vs cg) and H exchange (uncached) changed.
// breg: 32 us8 = 128 VGPR of W_hh resident for all 31 steps (no call sites).
__global__ void __launch_bounds__(256, 1) k_rnn4(const u16* __restrict__ Whh16,
    const float* __restrict__ gatesx, const int* __restrict__ wsI,
    u16* __restrict__ Hbuf, unsigned* __restrict__ bar){
  __shared__ __align__(16) float gl[4096];   // 4 gates x 64m x 16dim
  const int tid = threadIdx.x, wave = tid >> 6, lane = tid & 63, blk = blockIdx.x;
  const int l15 = lane & 15, lq = lane >> 4;
  const int m = tid >> 2, d4 = (tid & 3) * 4;
  const int dl = wsI[64 + m];

  // ---- prologue: initial cell (h=c=0) for this thread's 4 dims of row m ----
  float c4[4], h4[4];
  {
    const float* gx0 = gatesx + (size_t)m * 4096 + blk * 16 + d4;
    f32x4 iv = *(const f32x4*)(gx0);
    f32x4 gv = *(const f32x4*)(gx0 + 2048);
    f32x4 ov = *(const f32x4*)(gx0 + 3072);
#pragma unroll
    for(int e = 0; e < 4; ++e){
      c4[e] = sigf(iv[e]) * tanhf_(gv[e]);   // f*c vanishes (c=0)
      h4[e] = sigf(ov[e]) * tanhf_(c4[e]);
    }
    stH(Hbuf + (size_t)m * 1024 + blk * 16 + d4, pack4bf(h4));
  }
  // ---- this wave's W_hh rows into registers: row = wave*1024 + blk*16 + l15 ----
  us8 breg[32];
  {
    const u16* Bp = Whh16 + ((size_t)wave * 1024 + blk * 16 + l15) * 1024 + lq * 8;
#pragma unroll
    for(int kt = 0; kt < 32; ++kt) breg[kt] = *(const us8*)(Bp + kt * 32);
  }
  gbar(bar, 64u, tid);                      // H(t=0) in L3, all blocks arrived

#pragma unroll 1
  for(int t = 0; t < 31; ++t){
    const u16* Ht = Hbuf + (size_t)t * 65536 + lq * 8;
    f32x4 acc[4] = {};
    // depth-1 software prefetch of the 4 H fragments per K-chunk
    us8 a0[4], a1[4];
#pragma unroll
    for(int mi = 0; mi < 4; ++mi)
      a0[mi] = ldH8(Ht + (size_t)(mi * 16 + l15) * 1024);
#pragma unroll
    for(int kt = 0; kt < 32; ++kt){
      if(kt < 31){
#pragma unroll
        for(int mi = 0; mi < 4; ++mi)
          a1[mi] = ldH8(Ht + (size_t)(mi * 16 + l15) * 1024 + (kt + 1) * 32);
      }
#pragma unroll
      for(int mi = 0; mi < 4; ++mi)
        acc[mi] = mfma16(a0[mi], breg[kt], acc[mi]);
#pragma unroll
      for(int mi = 0; mi < 4; ++mi) a0[mi] = a1[mi];
    }
    // ---- cross-wave gate exchange via LDS (wave = gate) ----
#pragma unroll
    for(int mi = 0; mi < 4; ++mi)
#pragma unroll
      for(int v = 0; v < 4; ++v)
        gl[wave * 1024 + (mi * 16 + lq * 4 + v) * 16 + l15] = acc[mi][v];
    __syncthreads();

    const float* gx = gatesx + ((size_t)(t + 1) * 64 + m) * 4096 + blk * 16 + d4;
    f32x4 gg[4];
#pragma unroll
    for(int g = 0; g < 4; ++g){
      f32x4 s = *(const f32x4*)&gl[g * 1024 + m * 16 + d4];
      gg[g] = s + *(const f32x4*)(gx + (size_t)g * 1024);
    }
    if(t < dl){
#pragma unroll
      for(int e = 0; e < 4; ++e){
        const float cn = sigf(gg[1][e]) * c4[e] + sigf(gg[0][e]) * tanhf_(gg[2][e]);
        c4[e] = cn;
        h4[e] = sigf(gg[3][e]) * tanhf_(cn);
      }
    }
    stH(Hbuf + ((size_t)(t + 1) * 64 + m) * 1024 + blk * 16 + d4, pack4bf(h4));
    if(t < 30) gbar(bar, 64u * (t + 2), tid);   // kernel boundary covers t=30
  }
}

// ---------------- K6: preds = H @ fc_W^T + fc_b, masked; XCD-chunked swizzle ----------------
__global__ void __launch_bounds__(256) k_gemm_fc(const u16* __restrict__ H,
    const void* __restrict__ fcW, const u16* __restrict__ fcW16, const int useW16,
    const void* __restrict__ fcb, const int* __restrict__ declen,
    const int* __restrict__ flags, void* __restrict__ out){
  __shared__ u16 As[4096], Bs[4096];
  const int tid = threadIdx.x, wave = tid >> 6, lane = tid & 63;
  const int bid = blockIdx.x;
  const int L = (bid & 7) * 500 + (bid >> 3);
  const int bm = L & 15, bn = L >> 4;
  const int mq = (wave >> 1) * 64, nq = (wave & 1) * 64;
  const int l15 = lane & 15, lq = lane >> 4;
  const int f32 = flags[0];
  const int bf32 = useW16 ? 0 : f32;
  f32x4 acc[4][4] = {};
  const int amax0 = 1983 - bm * 128;
  const void* Bbase = useW16 ? (const void*)(fcW16 + (size_t)bn * 128 * 1024)
      : (f32 ? (const void*)((const float*)fcW + (size_t)bn * 128 * 1024)
             : (const void*)((const u16*)fcW + (size_t)bn * 128 * 1024));
  gemm_main(H + (size_t)bm * 128 * 1024, Bbase, bf32,
            amax0 > 127 ? 127 : amax0, As, Bs, acc);
  const int rowb = bm * 128 + mq, colb = bn * 128 + nq;
  int   col[4];
  float bias[4];
#pragma unroll
  for(int j = 0; j < 4; ++j){
    col[j] = colb + j * 16 + l15;
    bias[j] = ldf(fcb, f32, col[j]);
  }
#pragma unroll
  for(int i = 0; i < 4; ++i)
#pragma unroll
    for(int v = 0; v < 4; ++v){
      const int row = rowb + i * 16 + lq * 4 + v;     // row = t*64 + b
      if(row < 1984){
        const int t = row >> 6, b = row & 63;
        const bool act = (t < declen[b]);
        const size_t obase = (size_t)b * 992000 + (size_t)t * 32000;
#pragma unroll
        for(int j = 0; j < 4; ++j){
          const float val = act ? (acc[i][j][v] + bias[j]) : 0.f;
          if(f32) ((float*)out)[obase + col[j]] = val;
          else    ((u16*)out)[obase + col[j]] = f2bf(val);
        }
      }
    }
}

extern "C" void kernel_launch(void* const* d_in, const int* in_sizes, int n_in,
                              void* d_out, int out_size, void* d_ws, size_t ws_size,
                              hipStream_t stream){
  const void* enc = d_in[0];
  const int*  caps = (const int*)d_in[1];
  const int*  lens = (const int*)d_in[2];
  const void* emb = d_in[3];
  const void* Wih = d_in[4];
  const void* Whh = d_in[5];
  const void* bih = d_in[6];
  const void* bhh = d_in[7];
  const void* fcW = d_in[8];
  const void* fcb = d_in[9];

  // Big scratch in d_out's preds region (dead until k_gemm_fc overwrites it):
  float* gatesx = (float*)d_out;                                   // 32 MB fp32 @ +0
  u16*   Xbuf   = (u16*)((char*)d_out + (size_t)32*1024*1024);     // 4 MB bf16 @ +32MB
  u16*   Whh16  = (u16*)((char*)d_out + (size_t)36*1024*1024);     // 8 MB bf16 @ +36MB
  u16*   Wih16  = (u16*)((char*)d_out + (size_t)36*1024*1024 + 8388608); // 8 MB bf16
  // Small persistent scratch in d_ws:
  char* ws = (char*)d_ws;
  int*      flags = (int*)ws;                                      // [0]=fp32?, [1]=int64?
  unsigned* bar   = (unsigned*)(ws + 192);                         // grid barrier counter
  int*      wsI   = (int*)(ws + 256);                              // [0..63] sort_ind, [64..127] declen
  u16*      Hbuf  = (u16*)(ws + (size_t)512*1024);                 // 2048x1024 bf16 = 4 MB
  u16*      fcW16 = (u16*)(ws + (size_t)8*1024*1024);              // 65.5 MB bf16 (optional)
  const int useFc16 = (ws_size >= (size_t)74*1024*1024) ? 1 : 0;

  hipLaunchKernelGGL(k_detect, dim3(1), dim3(64), 0, stream,
                     (const unsigned*)emb, lens, flags);
  hipLaunchKernelGGL(k_setup, dim3(1), dim3(64), 0, stream, lens, wsI, flags, d_out);
  hipLaunchKernelGGL(k_conv16, dim3(2048), dim3(256), 0, stream, Wih, flags, Wih16, 524288);
  hipLaunchKernelGGL(k_conv16, dim3(2048), dim3(256), 0, stream, Whh, flags, Whh16, 524288);
  if(useFc16)
    hipLaunchKernelGGL(k_conv16, dim3(4096), dim3(256), 0, stream, fcW, flags, fcW16, 4096000);
  hipLaunchKernelGGL(k_gather, dim3(2048), dim3(256), 0, stream, enc, caps, emb, wsI, flags, Xbuf);
  hipLaunchKernelGGL(k_gemm_gates, dim3(16, 32), dim3(256), 0, stream, Xbuf, Wih16, bih, bhh, flags, gatesx);

  {
    const u16* a0 = Whh16; const float* a1 = gatesx; const int* a2 = wsI;
    u16* a3 = Hbuf; unsigned* a4 = bar;
    void* kargs[] = {(void*)&a0, (void*)&a1, (void*)&a2, (void*)&a3, (void*)&a4};
    hipLaunchCooperativeKernel((const void*)k_rnn4, dim3(64), dim3(256), kargs, 0, stream);
  }

  hipLaunchKernelGGL(k_gemm_fc, dim3(4000), dim3(256), 0, stream,
                     Hbuf + (size_t)64 * 1024, fcW, fcW16, useFc16, fcb, wsI + 64, flags, d_out);
}

// Round 6
// 1150.606 us; speedup vs baseline: 1.6110x; 1.6110x over previous
//
#include <hip/hip_runtime.h>
#include <cstddef>
#include <cstdint>

// B=64, T_CAP=32, V=32000, E=D=1024, gates=4096, t_dec=31.
// d_out: preds[64*31*32000] ++ decode_lengths[64] ++ sort_ind[64]  (float dtype detected at runtime).
// Runtime dtype dispatch: flags[0]=1 if floats are fp32 (else bf16), flags[1]=1 if ints are int64.
// When inputs are bf16, weight-conversion kernels early-exit and GEMMs read the originals.
// Scratch layout in d_out's preds region (dead until k_gemm_fc overwrites it; region >= 121MB):
//   gatesx fp32 [0,32MB) ++ Xbuf bf16 [32,36MB) ++ Whh16 bf16 [36,44.4MB) ++ Wih16 bf16 [44.4,52.8MB)
// d_ws: flags(+bar)+wsI+Hbuf (~4.5MB) ++ (optional, if ws_size>=74MB) fcW16 bf16 @ +8MB (65.5MB).
#define PRED_N 63488000

typedef unsigned short u16;
typedef unsigned long long u64;
typedef __attribute__((ext_vector_type(8))) unsigned short us8;
typedef __attribute__((ext_vector_type(4))) float f32x4;
typedef __attribute__((ext_vector_type(8))) __bf16 bf16x8;

__device__ __forceinline__ float bf2f(u16 h){
  unsigned u = ((unsigned)h) << 16;
  return __builtin_bit_cast(float, u);
}
__device__ __forceinline__ u16 f2bf(float f){
  unsigned u = __builtin_bit_cast(unsigned, f);
  u += 0x7FFFu + ((u >> 16) & 1u);
  return (u16)(u >> 16);
}
__device__ __forceinline__ float sigf(float x){ return 1.f/(1.f + __expf(-x)); }
__device__ __forceinline__ float tanhf_(float x){ return 1.f - 2.f/(__expf(2.f*x) + 1.f); }

__device__ __forceinline__ f32x4 mfma16(us8 a, us8 b, f32x4 c){
  return __builtin_amdgcn_mfma_f32_16x16x32_bf16(
      __builtin_bit_cast(bf16x8, a), __builtin_bit_cast(bf16x8, b), c, 0, 0, 0);
}
__device__ __forceinline__ u64 pack4bf(const float* h){
  return (u64)f2bf(h[0]) | ((u64)f2bf(h[1]) << 16)
       | ((u64)f2bf(h[2]) << 32) | ((u64)f2bf(h[3]) << 48);
}
__device__ __forceinline__ us8 pack8(float4 a, float4 b){
  us8 r;
  r[0]=f2bf(a.x); r[1]=f2bf(a.y); r[2]=f2bf(a.z); r[3]=f2bf(a.w);
  r[4]=f2bf(b.x); r[5]=f2bf(b.y); r[6]=f2bf(b.z); r[7]=f2bf(b.w);
  return r;
}
// scalar read of a float array of unknown dtype
__device__ __forceinline__ float ldf(const void* p, int f32, int i){
  return f32 ? ((const float*)p)[i] : bf2f(((const u16*)p)[i]);
}
__device__ __forceinline__ int ldi(const int* p, int i64, int i){
  return i64 ? p[2*i] : p[i];   // little-endian low word; values < 2^31
}
// uncached (L1/L2-bypassing, L3-coherent) H exchange for the persistent RNN kernel
__device__ __forceinline__ void stH(u16* p, u64 v){
  __hip_atomic_store((u64*)p, v, __ATOMIC_RELAXED, __HIP_MEMORY_SCOPE_AGENT);
}
__device__ __forceinline__ us8 ldH8(const u16* p){
  union { u64 q[2]; us8 v; } u;
  u.q[0] = __hip_atomic_load((const u64*)p,       __ATOMIC_RELAXED, __HIP_MEMORY_SCOPE_AGENT);
  u.q[1] = __hip_atomic_load((const u64*)(p + 4), __ATOMIC_RELAXED, __HIP_MEMORY_SCOPE_AGENT);
  return u.v;
}

// ---------------- K0: dtype detector (+ barrier reset for this run) ----------------
__global__ void k_detect(const unsigned* __restrict__ embw, const int* __restrict__ lenw,
                         int* __restrict__ flags){
  if(threadIdx.x == 0){
    int hits = 0;
    for(int i = 0; i < 16; ++i){
      unsigned w = embw[i];
      int elo = (w >> 7) & 0xFF, ehi = (w >> 23) & 0xFF;
      hits += (elo >= 112 && elo <= 133) && (ehi >= 112 && ehi <= 133);
    }
    flags[0] = (hits >= 12) ? 0 : 1;        // 1 = fp32 floats
    int orv = 0;
    for(int i = 0; i < 4; ++i) orv |= lenw[2*i + 1];
    flags[1] = (orv == 0) ? 1 : 0;          // 1 = int64 ints
    // reset grid-barrier counter (uncached store so k_rnn5's uncached RMWs see it)
    __hip_atomic_store((unsigned*)(flags + 48), 0u, __ATOMIC_RELAXED, __HIP_MEMORY_SCOPE_AGENT);
  }
}

// ---------------- K1: stable descending sort + tail outputs ----------------
__global__ void k_setup(const int* __restrict__ lens, int* __restrict__ wsI,
                        const int* __restrict__ flags, void* __restrict__ out){
  const int i = threadIdx.x;                // 64 threads
  const int f32 = flags[0], i64 = flags[1];
  const int li = ldi(lens, i64, i);
  int rank = 0;
  for(int j = 0; j < 64; ++j){
    const int lj = ldi(lens, i64, j);
    rank += (lj > li) || (lj == li && j < i);   // stable descending
  }
  wsI[rank]      = i;                       // sort_ind
  wsI[64 + rank] = li - 1;                  // decode_lengths (sorted order)
  if(f32){
    ((float*)out)[PRED_N + rank]      = (float)(li - 1);
    ((float*)out)[PRED_N + 64 + rank] = (float)i;
  } else {
    ((u16*)out)[PRED_N + rank]      = f2bf((float)(li - 1));
    ((u16*)out)[PRED_N + 64 + rank] = f2bf((float)i);
  }
}

// ---------------- K1b: weight convert fp32 -> bf16 RNE (no-op when already bf16) ----------------
__global__ void __launch_bounds__(256) k_conv16(const void* __restrict__ W,
    const int* __restrict__ flags, u16* __restrict__ dst, int n8){
  if(!flags[0]) return;                     // bf16 inputs: originals are used directly
  const int stride = gridDim.x * 256;
  for(int i = blockIdx.x * 256 + threadIdx.x; i < n8; i += stride){
    const float4* s = (const float4*)W + 2 * (size_t)i;
    ((us8*)dst)[i] = pack8(s[0], s[1]);
  }
}

// ---------------- K2: build X (2048x1024 bf16), row t*64+b ----------------
__global__ void __launch_bounds__(256) k_gather(const void* __restrict__ enc,
    const int* __restrict__ caps, const void* __restrict__ emb,
    const int* __restrict__ wsI, const int* __restrict__ flags, u16* __restrict__ X){
  const int r = blockIdx.x, t = r >> 6, b = r & 63;
  const int f32 = flags[0], i64 = flags[1];
  const int sb = wsI[b];
  const size_t rowoff = (t == 0) ? (size_t)sb * 1024
                                 : (size_t)ldi(caps, i64, sb * 32 + (t - 1)) * 1024;
  const void* base = (t == 0) ? enc : emb;
  u16* dst = X + (size_t)r * 1024;
  if(f32){
    const float4* src = (const float4*)((const float*)base + rowoff);
    float4 v = src[threadIdx.x];            // 4 floats per thread
    u64 w = (u64)f2bf(v.x) | ((u64)f2bf(v.y) << 16)
          | ((u64)f2bf(v.z) << 32) | ((u64)f2bf(v.w) << 48);
    ((u64*)dst)[threadIdx.x] = w;
  } else {
    const uint2* src = (const uint2*)((const u16*)base + rowoff);
    ((uint2*)dst)[threadIdx.x] = src[threadIdx.x];  // 4 bf16 per thread
  }
}

// ---------------- 128x128 K=1024 MFMA mainloop; XOR-swizzled LDS (T2) ----------------
__device__ __forceinline__ void gemm_main(const u16* __restrict__ A, const void* __restrict__ Bv,
    int bF32, int arowmax, u16* As, u16* Bs, f32x4 (&acc)[4][4]){
  const int tid = threadIdx.x, wave = tid >> 6, lane = tid & 63;
  const int mq = (wave >> 1) * 64, nq = (wave & 1) * 64;
  const int l15 = lane & 15, lq = lane >> 4;
  const int r0 = lane >> 2, c0 = (lane & 3) * 8;     // within a 16x32 chunk
  const int sww = ((r0 & 7) << 3);                   // write-side swizzle
  const int swr = ((l15 & 7) << 3);                  // read-side swizzle
  const u16* Bb = (const u16*)Bv; const float* Bf = (const float*)Bv;
  for(int k0 = 0; k0 < 1024; k0 += 32){
    us8 av[2], bv[2];
#pragma unroll
    for(int c2 = 0; c2 < 2; ++c2){
      const int chunk = wave * 2 + c2;               // 8 chunks of 16 rows
      int ar = chunk * 16 + r0; if(ar > arowmax) ar = arowmax;
      av[c2] = *(const us8*)(A + (size_t)ar * 1024 + k0 + c0);
      const size_t bo = (size_t)(chunk * 16 + r0) * 1024 + k0 + c0;
      if(bF32){
        const float* p = Bf + bo;
        bv[c2] = pack8(*(const float4*)p, *(const float4*)(p + 4));
      } else {
        bv[c2] = *(const us8*)(Bb + bo);
      }
    }
    __syncthreads();   // previous iteration's LDS reads complete
#pragma unroll
    for(int c2 = 0; c2 < 2; ++c2){
      const int chunk = wave * 2 + c2;
      *(us8*)&As[(chunk * 512 + r0 * 32 + c0) ^ sww] = av[c2];
      *(us8*)&Bs[(chunk * 512 + r0 * 32 + c0) ^ sww] = bv[c2];
    }
    __syncthreads();
    us8 af[4], bfv[4];
#pragma unroll
    for(int i = 0; i < 4; ++i){
      af[i]  = *(const us8*)&As[((mq + i * 16 + l15) * 32 + lq * 8) ^ swr];
      bfv[i] = *(const us8*)&Bs[((nq + i * 16 + l15) * 32 + lq * 8) ^ swr];
    }
#pragma unroll
    for(int i = 0; i < 4; ++i)
#pragma unroll
      for(int j = 0; j < 4; ++j)
        acc[i][j] = mfma16(af[i], bfv[j], acc[i][j]);
  }
}

// ---------------- K3: gates_x = X @ W_ih^T + (b_ih + b_hh), fp32 ----------------
__global__ void __launch_bounds__(256) k_gemm_gates(const u16* __restrict__ X,
    const void* __restrict__ Wih, const u16* __restrict__ Wih16c,
    const void* __restrict__ bih, const void* __restrict__ bhh,
    const int* __restrict__ flags, float* __restrict__ gatesx){
  __shared__ u16 As[4096], Bs[4096];
  const int tid = threadIdx.x, wave = tid >> 6, lane = tid & 63;
  const int bm = blockIdx.x, bn = blockIdx.y;
  const int mq = (wave >> 1) * 64, nq = (wave & 1) * 64;
  const int l15 = lane & 15, lq = lane >> 4;
  const int f32 = flags[0];
  const u16* Wb = f32 ? Wih16c : (const u16*)Wih;   // both bf16 layouts
  f32x4 acc[4][4] = {};
  gemm_main(X + (size_t)bm * 128 * 1024, Wb + (size_t)bn * 128 * 1024, 0, 127, As, Bs, acc);
  const int rowb = bm * 128 + mq, colb = bn * 128 + nq;
#pragma unroll
  for(int j = 0; j < 4; ++j){
    const int col = colb + j * 16 + l15;
    const float bias = ldf(bih, f32, col) + ldf(bhh, f32, col);
#pragma unroll
    for(int i = 0; i < 4; ++i)
#pragma unroll
      for(int v = 0; v < 4; ++v){
        const int row = rowb + i * 16 + lq * 4 + v;
        gatesx[(size_t)row * 4096 + col] = acc[i][j][v] + bias;
      }
  }
}

// ---------------- relaxed grid barrier: execution ordering ONLY, zero cache ops ----------------
// H exchange is uncached (agent-scope atomics -> L3), so no wbl2/inv is needed.
// __syncthreads() drains each wave's vmcnt (uncached stores are at L3 before the bump);
// the packers (tid<64) are in wave 0 = tid 0's wave, so lane 0's add is ordered after them.
__device__ __forceinline__ void gbar(unsigned* bar, unsigned tgt, int tid){
  __syncthreads();
  if(tid == 0){
    __hip_atomic_fetch_add(bar, 1u, __ATOMIC_RELAXED, __HIP_MEMORY_SCOPE_AGENT);
    while(__hip_atomic_load(bar, __ATOMIC_RELAXED, __HIP_MEMORY_SCOPE_AGENT) < tgt)
      __builtin_amdgcn_s_sleep(2);
  }
  __syncthreads();
  asm volatile("" ::: "memory");
}

// ---------------- K5: persistent RNN — r1's 256-block geometry + relaxed barrier ----------------
// 256 blocks x 256 threads (1/CU, cooperative). Block blk owns dims [blk*4,blk*4+4) x 4 gates
// = 16 N-rows of W_hh; wave w owns K-slice [w*256,w*256+256). W slice resident in 32 VGPRs.
// c,h live in registers (thread = one (m,dim) scalar). Uncached H exchange; one relaxed
// grid barrier per step (no cache maintenance — that was r2/r5's 36us/step).
__global__ void __launch_bounds__(256, 1) k_rnn5(const void* __restrict__ Whh,
    const u16* __restrict__ Whh16c, const float* __restrict__ gatesx,
    const int* __restrict__ wsI, const int* __restrict__ flags,
    u16* __restrict__ Hbuf, unsigned* __restrict__ bar){
  __shared__ __align__(16) float red[4096];   // 4 waves x 64m x 16n partials
  __shared__ __align__(16) float hl[256];     // h staging for packed u64 stores
  const int tid = threadIdx.x, wave = tid >> 6, lane = tid & 63, blk = blockIdx.x;
  const int l15 = lane & 15, lq = lane >> 4;
  const int m = tid >> 2, dr = tid & 3;
  const int dim = blk * 4 + dr;
  const int dl = wsI[64 + m];
  const u16* W = flags[0] ? Whh16c : (const u16*)Whh;

  // ---- prologue: initial cell (h=c=0) for this thread's (m, dim) ----
  float c1, h1;
  {
    const float* gx0 = gatesx + (size_t)m * 4096 + dim;
    const float iv = gx0[0], gv = gx0[2048], ov = gx0[3072];
    c1 = sigf(iv) * tanhf_(gv);             // f*c vanishes (c=0)
    h1 = sigf(ov) * tanhf_(c1);
  }
  hl[m * 4 + dr] = h1;
  // ---- W_hh fragments resident: B-row = l15 -> (gate l15>>2, dim blk*4+(l15&3)) ----
  const int brow = (l15 >> 2) * 1024 + blk * 4 + (l15 & 3);
  us8 breg[8];
  {
    const u16* Bp = W + (size_t)brow * 1024 + wave * 256 + lq * 8;
#pragma unroll
    for(int kt = 0; kt < 8; ++kt) breg[kt] = *(const us8*)(Bp + kt * 32);
  }
  __syncthreads();
  if(tid < 64) stH(Hbuf + (size_t)tid * 1024 + blk * 4, pack4bf(&hl[tid * 4]));
  gbar(bar, 256u, tid);                     // H(0) at L3, all blocks arrived

#pragma unroll 1
  for(int t = 0; t < 31; ++t){
    // ---- prefetch ALL 32 H fragments (one exposed L3 latency), then MFMA ----
    const u16* Ht = Hbuf + (size_t)t * 65536 + wave * 256 + lq * 8;
    us8 af[32];
#pragma unroll
    for(int kt = 0; kt < 8; ++kt)
#pragma unroll
      for(int mi = 0; mi < 4; ++mi)
        af[kt * 4 + mi] = ldH8(Ht + (size_t)(mi * 16 + l15) * 1024 + kt * 32);
    f32x4 acc[4] = {};
#pragma unroll
    for(int kt = 0; kt < 8; ++kt)
#pragma unroll
      for(int mi = 0; mi < 4; ++mi)
        acc[mi] = mfma16(af[kt * 4 + mi], breg[kt], acc[mi]);
    // ---- cross-wave K-reduce via LDS ----
#pragma unroll
    for(int mi = 0; mi < 4; ++mi)
#pragma unroll
      for(int v = 0; v < 4; ++v)
        red[wave * 1024 + (mi * 16 + lq * 4 + v) * 16 + l15] = acc[mi][v];
    __syncthreads();
    // ---- per-thread (m, dim) gate finish ----
    const float* gx = gatesx + ((size_t)(t + 1) * 64 + m) * 4096 + dim;
    float g4[4];
#pragma unroll
    for(int g = 0; g < 4; ++g){
      const int n = g * 4 + dr;
      g4[g] = red[m * 16 + n] + red[1024 + m * 16 + n]
            + red[2048 + m * 16 + n] + red[3072 + m * 16 + n]
            + gx[(size_t)g * 1024];
    }
    if(t < dl){
      const float cn = sigf(g4[1]) * c1 + sigf(g4[0]) * tanhf_(g4[2]);
      c1 = cn;
      h1 = sigf(g4[3]) * tanhf_(cn);
    }
    hl[m * 4 + dr] = h1;
    __syncthreads();
    if(tid < 64) stH(Hbuf + ((size_t)(t + 1) * 64 + tid) * 1024 + blk * 4, pack4bf(&hl[tid * 4]));
    if(t < 30) gbar(bar, 256u * (t + 2), tid);   // kernel boundary covers t=30
  }
}

// ---------------- K6: preds = H @ fc_W^T + fc_b, masked; coalesced LDS epilogue ----------------
__global__ void __launch_bounds__(256) k_gemm_fc(const u16* __restrict__ H,
    const void* __restrict__ fcW, const u16* __restrict__ fcW16, const int useW16,
    const void* __restrict__ fcb, const int* __restrict__ declen,
    const int* __restrict__ flags, void* __restrict__ out){
  __shared__ u16 smem[8192];                // mainloop: As|Bs; epilogue: 32x128 stage
  u16* As = smem; u16* Bs = smem + 4096;
  const int tid = threadIdx.x, wave = tid >> 6, lane = tid & 63;
  const int bid = blockIdx.x;
  const int L = (bid & 7) * 500 + (bid >> 3);    // XCD-chunked bijective swizzle
  const int bm = L & 15, bn = L >> 4;            // bm innermost: B-strip L2-resident
  const int mq = (wave >> 1) * 64, nq = (wave & 1) * 64;
  const int l15 = lane & 15, lq = lane >> 4;
  const int f32 = flags[0];
  const void* Bbase; int bf32;
  if(f32){
    if(useW16){ Bbase = fcW16 + (size_t)bn * 131072; bf32 = 0; }
    else      { Bbase = (const float*)fcW + (size_t)bn * 131072; bf32 = 1; }
  } else      { Bbase = (const u16*)fcW + (size_t)bn * 131072; bf32 = 0; }  // already bf16
  f32x4 acc[4][4] = {};
  const int amax0 = 1983 - bm * 128;
  gemm_main(H + (size_t)bm * 131072, Bbase, bf32, amax0 > 127 ? 127 : amax0, As, Bs, acc);
  float bias[4];
#pragma unroll
  for(int j = 0; j < 4; ++j) bias[j] = ldf(fcb, f32, bn * 128 + nq + j * 16 + l15);
  __syncthreads();
  // 4 chunks of 32 rows x 128 cols: stage (masked) -> coalesced 16B stores
  for(int i = 0; i < 4; ++i){
#pragma unroll
    for(int v = 0; v < 4; ++v){
      const int row = bm * 128 + mq + i * 16 + lq * 4 + v;
      const int s = (wave >> 1) * 16 + lq * 4 + v;       // staged row 0..31
      bool act = false;
      if(row < 1984) act = ((row >> 6) < declen[row & 63]);
#pragma unroll
      for(int j = 0; j < 4; ++j){
        const float val = act ? (acc[i][j][v] + bias[j]) : 0.f;
        const int cl = nq + j * 16 + l15;
        if(f32) ((float*)smem)[s * 128 + cl] = val;      // 16KB (As+Bs)
        else    smem[s * 128 + cl] = f2bf(val);          // 8KB
      }
    }
    __syncthreads();
    if(f32){
#pragma unroll
      for(int p = 0; p < 4; ++p){
        const int idx = p * 256 + tid;
        const int s = idx >> 5, c = (idx & 31) * 4;
        const int grow = bm * 128 + (s >> 4) * 64 + i * 16 + (s & 15);
        if(grow < 1984){
          const int tt = grow >> 6, b = grow & 63;
          *(float4*)((float*)out + (size_t)b * 992000 + (size_t)tt * 32000 + bn * 128 + c)
              = *(const float4*)((const float*)smem + s * 128 + c);
        }
      }
    } else {
#pragma unroll
      for(int p = 0; p < 2; ++p){
        const int idx = p * 256 + tid;
        const int s = idx >> 4, c = (idx & 15) * 8;
        const int grow = bm * 128 + (s >> 4) * 64 + i * 16 + (s & 15);
        if(grow < 1984){
          const int tt = grow >> 6, b = grow & 63;
          *(us8*)((u16*)out + (size_t)b * 992000 + (size_t)tt * 32000 + bn * 128 + c)
              = *(const us8*)(smem + s * 128 + c);
        }
      }
    }
    __syncthreads();
  }
}

extern "C" void kernel_launch(void* const* d_in, const int* in_sizes, int n_in,
                              void* d_out, int out_size, void* d_ws, size_t ws_size,
                              hipStream_t stream){
  const void* enc = d_in[0];
  const int*  caps = (const int*)d_in[1];
  const int*  lens = (const int*)d_in[2];
  const void* emb = d_in[3];
  const void* Wih = d_in[4];
  const void* Whh = d_in[5];
  const void* bih = d_in[6];
  const void* bhh = d_in[7];
  const void* fcW = d_in[8];
  const void* fcb = d_in[9];

  // Big scratch in d_out's preds region (dead until k_gemm_fc overwrites it):
  float* gatesx = (float*)d_out;                                   // 32 MB fp32 @ +0
  u16*   Xbuf   = (u16*)((char*)d_out + (size_t)32*1024*1024);     // 4 MB bf16 @ +32MB
  u16*   Whh16  = (u16*)((char*)d_out + (size_t)36*1024*1024);     // 8 MB bf16 @ +36MB
  u16*   Wih16  = (u16*)((char*)d_out + (size_t)36*1024*1024 + 8388608); // 8 MB bf16
  // Small persistent scratch in d_ws:
  char* ws = (char*)d_ws;
  int*      flags = (int*)ws;                                      // [0]=fp32?, [1]=int64?
  unsigned* bar   = (unsigned*)(ws + 192);                         // grid barrier counter
  int*      wsI   = (int*)(ws + 256);                              // [0..63] sort_ind, [64..127] declen
  u16*      Hbuf  = (u16*)(ws + (size_t)512*1024);                 // 2048x1024 bf16 = 4 MB
  u16*      fcW16 = (u16*)(ws + (size_t)8*1024*1024);              // 65.5 MB bf16 (optional)
  const int useFc16 = (ws_size >= (size_t)74*1024*1024) ? 1 : 0;

  hipLaunchKernelGGL(k_detect, dim3(1), dim3(64), 0, stream,
                     (const unsigned*)emb, lens, flags);
  hipLaunchKernelGGL(k_setup, dim3(1), dim3(64), 0, stream, lens, wsI, flags, d_out);
  hipLaunchKernelGGL(k_conv16, dim3(2048), dim3(256), 0, stream, Wih, flags, Wih16, 524288);
  hipLaunchKernelGGL(k_conv16, dim3(2048), dim3(256), 0, stream, Whh, flags, Whh16, 524288);
  if(useFc16)
    hipLaunchKernelGGL(k_conv16, dim3(4096), dim3(256), 0, stream, fcW, flags, fcW16, 4096000);
  hipLaunchKernelGGL(k_gather, dim3(2048), dim3(256), 0, stream, enc, caps, emb, wsI, flags, Xbuf);
  hipLaunchKernelGGL(k_gemm_gates, dim3(16, 32), dim3(256), 0, stream,
                     Xbuf, Wih, Wih16, bih, bhh, flags, gatesx);

  {
    const void* a0 = Whh; const u16* a1 = Whh16; const float* a2 = gatesx;
    const int* a3 = wsI; const int* a4 = flags; u16* a5 = Hbuf; unsigned* a6 = bar;
    void* kargs[] = {(void*)&a0, (void*)&a1, (void*)&a2, (void*)&a3,
                     (void*)&a4, (void*)&a5, (void*)&a6};
    hipLaunchCooperativeKernel((const void*)k_rnn5, dim3(256), dim3(256), kargs, 0, stream);
  }

  hipLaunchKernelGGL(k_gemm_fc, dim3(4000), dim3(256), 0, stream,
                     Hbuf + (size_t)64 * 1024, fcW, fcW16, useFc16, fcb, wsI + 64, flags, d_out);
}

// Round 7
// 1123.051 us; speedup vs baseline: 1.6505x; 1.0245x over previous
//
#include <hip/hip_runtime.h>
#include <cstddef>
#include <cstdint>

// B=64, T_CAP=32, V=32000, E=D=1024, gates=4096, t_dec=31.
// d_out: preds[64*31*32000] ++ decode_lengths[64] ++ sort_ind[64]  (float dtype detected at runtime).
// Runtime dtype dispatch: flags[0]=1 if floats are fp32 (else bf16), flags[1]=1 if ints are int64.
// When inputs are bf16, weight-conversion kernels early-exit and GEMMs read the originals.
// Scratch layout in d_out's preds region (dead until k_gemm_fc overwrites it; region >= 121MB):
//   gatesx fp32 [0,32MB) ++ Xbuf bf16 [32,36MB) ++ Whh16 bf16 [36,44.4MB) ++ Wih16 bf16 [44.4,52.8MB)
// d_ws: flags+flagv+wsI+Hbuf (~4.5MB) ++ (optional, if ws_size>=74MB) fcW16 bf16 @ +8MB (65.5MB).
#define PRED_N 63488000

typedef unsigned short u16;
typedef unsigned long long u64;
typedef __attribute__((ext_vector_type(8))) unsigned short us8;
typedef __attribute__((ext_vector_type(4))) float f32x4;
typedef __attribute__((ext_vector_type(8))) __bf16 bf16x8;

__device__ __forceinline__ float bf2f(u16 h){
  unsigned u = ((unsigned)h) << 16;
  return __builtin_bit_cast(float, u);
}
__device__ __forceinline__ u16 f2bf(float f){
  unsigned u = __builtin_bit_cast(unsigned, f);
  u += 0x7FFFu + ((u >> 16) & 1u);
  return (u16)(u >> 16);
}
__device__ __forceinline__ float sigf(float x){ return 1.f/(1.f + __expf(-x)); }
__device__ __forceinline__ float tanhf_(float x){ return 1.f - 2.f/(__expf(2.f*x) + 1.f); }

__device__ __forceinline__ f32x4 mfma16(us8 a, us8 b, f32x4 c){
  return __builtin_amdgcn_mfma_f32_16x16x32_bf16(
      __builtin_bit_cast(bf16x8, a), __builtin_bit_cast(bf16x8, b), c, 0, 0, 0);
}
__device__ __forceinline__ u64 pack4bf(const float* h){
  return (u64)f2bf(h[0]) | ((u64)f2bf(h[1]) << 16)
       | ((u64)f2bf(h[2]) << 32) | ((u64)f2bf(h[3]) << 48);
}
__device__ __forceinline__ us8 pack8(float4 a, float4 b){
  us8 r;
  r[0]=f2bf(a.x); r[1]=f2bf(a.y); r[2]=f2bf(a.z); r[3]=f2bf(a.w);
  r[4]=f2bf(b.x); r[5]=f2bf(b.y); r[6]=f2bf(b.z); r[7]=f2bf(b.w);
  return r;
}
// scalar read of a float array of unknown dtype
__device__ __forceinline__ float ldf(const void* p, int f32, int i){
  return f32 ? ((const float*)p)[i] : bf2f(((const u16*)p)[i]);
}
__device__ __forceinline__ int ldi(const int* p, int i64, int i){
  return i64 ? p[2*i] : p[i];   // little-endian low word; values < 2^31
}
// uncached (L1/L2-bypassing, L3-coherent) H exchange for the persistent RNN kernel
__device__ __forceinline__ void stH(u16* p, u64 v){
  __hip_atomic_store((u64*)p, v, __ATOMIC_RELAXED, __HIP_MEMORY_SCOPE_AGENT);
}
__device__ __forceinline__ us8 ldH8(const u16* p){
  union { u64 q[2]; us8 v; } u;
  u.q[0] = __hip_atomic_load((const u64*)p,       __ATOMIC_RELAXED, __HIP_MEMORY_SCOPE_AGENT);
  u.q[1] = __hip_atomic_load((const u64*)(p + 4), __ATOMIC_RELAXED, __HIP_MEMORY_SCOPE_AGENT);
  return u.v;
}

// ---------------- K0: dtype detector (+ barrier flag-array reset for this run) ----------------
__global__ void k_detect(const unsigned* __restrict__ embw, const int* __restrict__ lenw,
                         int* __restrict__ flags){
  const int tid = threadIdx.x;              // 64 threads
  // zero the 256-entry grid-barrier flag array (at flags+1024 int offset, byte +4096)
  for(int i = tid; i < 256; i += 64)
    __hip_atomic_store((unsigned*)(flags + 1024) + i, 0u,
                       __ATOMIC_RELAXED, __HIP_MEMORY_SCOPE_AGENT);
  if(tid == 0){
    int hits = 0;
    for(int i = 0; i < 16; ++i){
      unsigned w = embw[i];
      int elo = (w >> 7) & 0xFF, ehi = (w >> 23) & 0xFF;
      hits += (elo >= 112 && elo <= 133) && (ehi >= 112 && ehi <= 133);
    }
    flags[0] = (hits >= 12) ? 0 : 1;        // 1 = fp32 floats
    int orv = 0;
    for(int i = 0; i < 4; ++i) orv |= lenw[2*i + 1];
    flags[1] = (orv == 0) ? 1 : 0;          // 1 = int64 ints
  }
}

// ---------------- K1: stable descending sort + tail outputs ----------------
__global__ void k_setup(const int* __restrict__ lens, int* __restrict__ wsI,
                        const int* __restrict__ flags, void* __restrict__ out){
  const int i = threadIdx.x;                // 64 threads
  const int f32 = flags[0], i64 = flags[1];
  const int li = ldi(lens, i64, i);
  int rank = 0;
  for(int j = 0; j < 64; ++j){
    const int lj = ldi(lens, i64, j);
    rank += (lj > li) || (lj == li && j < i);   // stable descending
  }
  wsI[rank]      = i;                       // sort_ind
  wsI[64 + rank] = li - 1;                  // decode_lengths (sorted order)
  if(f32){
    ((float*)out)[PRED_N + rank]      = (float)(li - 1);
    ((float*)out)[PRED_N + 64 + rank] = (float)i;
  } else {
    ((u16*)out)[PRED_N + rank]      = f2bf((float)(li - 1));
    ((u16*)out)[PRED_N + 64 + rank] = f2bf((float)i);
  }
}

// ---------------- K1b: weight convert fp32 -> bf16 RNE (no-op when already bf16) ----------------
__global__ void __launch_bounds__(256) k_conv16(const void* __restrict__ W,
    const int* __restrict__ flags, u16* __restrict__ dst, int n8){
  if(!flags[0]) return;                     // bf16 inputs: originals are used directly
  const int stride = gridDim.x * 256;
  for(int i = blockIdx.x * 256 + threadIdx.x; i < n8; i += stride){
    const float4* s = (const float4*)W + 2 * (size_t)i;
    ((us8*)dst)[i] = pack8(s[0], s[1]);
  }
}

// ---------------- K2: build X (2048x1024 bf16), row t*64+b ----------------
__global__ void __launch_bounds__(256) k_gather(const void* __restrict__ enc,
    const int* __restrict__ caps, const void* __restrict__ emb,
    const int* __restrict__ wsI, const int* __restrict__ flags, u16* __restrict__ X){
  const int r = blockIdx.x, t = r >> 6, b = r & 63;
  const int f32 = flags[0], i64 = flags[1];
  const int sb = wsI[b];
  const size_t rowoff = (t == 0) ? (size_t)sb * 1024
                                 : (size_t)ldi(caps, i64, sb * 32 + (t - 1)) * 1024;
  const void* base = (t == 0) ? enc : emb;
  u16* dst = X + (size_t)r * 1024;
  if(f32){
    const float4* src = (const float4*)((const float*)base + rowoff);
    float4 v = src[threadIdx.x];            // 4 floats per thread
    u64 w = (u64)f2bf(v.x) | ((u64)f2bf(v.y) << 16)
          | ((u64)f2bf(v.z) << 32) | ((u64)f2bf(v.w) << 48);
    ((u64*)dst)[threadIdx.x] = w;
  } else {
    const uint2* src = (const uint2*)((const u16*)base + rowoff);
    ((uint2*)dst)[threadIdx.x] = src[threadIdx.x];  // 4 bf16 per thread
  }
}

// ---------------- 128x128 K=1024 MFMA mainloop; XOR-swizzled LDS (T2) ----------------
__device__ __forceinline__ void gemm_main(const u16* __restrict__ A, const void* __restrict__ Bv,
    int bF32, int arowmax, u16* As, u16* Bs, f32x4 (&acc)[4][4]){
  const int tid = threadIdx.x, wave = tid >> 6, lane = tid & 63;
  const int mq = (wave >> 1) * 64, nq = (wave & 1) * 64;
  const int l15 = lane & 15, lq = lane >> 4;
  const int r0 = lane >> 2, c0 = (lane & 3) * 8;     // within a 16x32 chunk
  const int sww = ((r0 & 7) << 3);                   // write-side swizzle
  const int swr = ((l15 & 7) << 3);                  // read-side swizzle
  const u16* Bb = (const u16*)Bv; const float* Bf = (const float*)Bv;
  for(int k0 = 0; k0 < 1024; k0 += 32){
    us8 av[2], bv[2];
#pragma unroll
    for(int c2 = 0; c2 < 2; ++c2){
      const int chunk = wave * 2 + c2;               // 8 chunks of 16 rows
      int ar = chunk * 16 + r0; if(ar > arowmax) ar = arowmax;
      av[c2] = *(const us8*)(A + (size_t)ar * 1024 + k0 + c0);
      const size_t bo = (size_t)(chunk * 16 + r0) * 1024 + k0 + c0;
      if(bF32){
        const float* p = Bf + bo;
        bv[c2] = pack8(*(const float4*)p, *(const float4*)(p + 4));
      } else {
        bv[c2] = *(const us8*)(Bb + bo);
      }
    }
    __syncthreads();   // previous iteration's LDS reads complete
#pragma unroll
    for(int c2 = 0; c2 < 2; ++c2){
      const int chunk = wave * 2 + c2;
      *(us8*)&As[(chunk * 512 + r0 * 32 + c0) ^ sww] = av[c2];
      *(us8*)&Bs[(chunk * 512 + r0 * 32 + c0) ^ sww] = bv[c2];
    }
    __syncthreads();
    us8 af[4], bfv[4];
#pragma unroll
    for(int i = 0; i < 4; ++i){
      af[i]  = *(const us8*)&As[((mq + i * 16 + l15) * 32 + lq * 8) ^ swr];
      bfv[i] = *(const us8*)&Bs[((nq + i * 16 + l15) * 32 + lq * 8) ^ swr];
    }
#pragma unroll
    for(int i = 0; i < 4; ++i)
#pragma unroll
      for(int j = 0; j < 4; ++j)
        acc[i][j] = mfma16(af[i], bfv[j], acc[i][j]);
  }
}

// ---------------- K3: gates_x = X @ W_ih^T + (b_ih + b_hh), fp32 ----------------
__global__ void __launch_bounds__(256) k_gemm_gates(const u16* __restrict__ X,
    const void* __restrict__ Wih, const u16* __restrict__ Wih16c,
    const void* __restrict__ bih, const void* __restrict__ bhh,
    const int* __restrict__ flags, float* __restrict__ gatesx){
  __shared__ u16 As[4096], Bs[4096];
  const int tid = threadIdx.x, wave = tid >> 6, lane = tid & 63;
  const int bm = blockIdx.x, bn = blockIdx.y;
  const int mq = (wave >> 1) * 64, nq = (wave & 1) * 64;
  const int l15 = lane & 15, lq = lane >> 4;
  const int f32 = flags[0];
  const u16* Wb = f32 ? Wih16c : (const u16*)Wih;   // both bf16 layouts
  f32x4 acc[4][4] = {};
  gemm_main(X + (size_t)bm * 128 * 1024, Wb + (size_t)bn * 128 * 1024, 0, 127, As, Bs, acc);
  const int rowb = bm * 128 + mq, colb = bn * 128 + nq;
#pragma unroll
  for(int j = 0; j < 4; ++j){
    const int col = colb + j * 16 + l15;
    const float bias = ldf(bih, f32, col) + ldf(bhh, f32, col);
#pragma unroll
    for(int i = 0; i < 4; ++i)
#pragma unroll
      for(int v = 0; v < 4; ++v){
        const int row = rowb + i * 16 + lq * 4 + v;
        gatesx[(size_t)row * 4096 + col] = acc[i][j][v] + bias;
      }
  }
}

// ---------------- contention-free broadcast grid barrier ----------------
// One flag word per block (no shared-line RMWs). Arrival: relaxed uncached store
// flag[bid]=tgt (all blocks in parallel). Completion: wave 0 of every block loads all
// 256 flags in parallel (2 u64 per lane) and __all()s the predicate — one L3 round
// trip per poll, zero serialization. Flags are monotone (tgt = t+1), no reset hazard.
// __syncthreads() before arrival drains vmcnt -> all uncached H stores are at L3.
__device__ __forceinline__ void gbar(unsigned* flagv, unsigned tgt, int tid, int bid){
  __syncthreads();
  if(tid < 64){
    if(tid == 0)
      __hip_atomic_store(flagv + bid, tgt, __ATOMIC_RELAXED, __HIP_MEMORY_SCOPE_AGENT);
    const u64* fp = (const u64*)flagv + tid * 2;
    for(;;){
      const u64 q0 = __hip_atomic_load(fp,     __ATOMIC_RELAXED, __HIP_MEMORY_SCOPE_AGENT);
      const u64 q1 = __hip_atomic_load(fp + 1, __ATOMIC_RELAXED, __HIP_MEMORY_SCOPE_AGENT);
      const bool ok = ((unsigned)q0 >= tgt) && ((unsigned)(q0 >> 32) >= tgt)
                   && ((unsigned)q1 >= tgt) && ((unsigned)(q1 >> 32) >= tgt);
      if(__all(ok)) break;
      __builtin_amdgcn_s_sleep(1);
    }
  }
  __syncthreads();
  asm volatile("" ::: "memory");
}

// ---------------- K5: persistent RNN — 256 blocks, broadcast barrier ----------------
// 256 blocks x 256 threads (1/CU, cooperative). Block blk owns dims [blk*4,blk*4+4) x 4 gates
// = 16 N-rows of W_hh; wave w owns K-slice [w*256,w*256+256). W slice resident in 32 VGPRs.
// c,h live in registers (thread = one (m,dim) scalar). Uncached H exchange; one broadcast
// barrier per step. gatesx loads hoisted to hide their latency under the H prefetch/MFMA.
__global__ void __launch_bounds__(256, 1) k_rnn6(const void* __restrict__ Whh,
    const u16* __restrict__ Whh16c, const float* __restrict__ gatesx,
    const int* __restrict__ wsI, const int* __restrict__ flags,
    u16* __restrict__ Hbuf, unsigned* __restrict__ flagv){
  __shared__ __align__(16) float red[4096];   // 4 waves x 64m x 16n partials
  __shared__ __align__(16) float hl[256];     // h staging for packed u64 stores
  const int tid = threadIdx.x, wave = tid >> 6, lane = tid & 63, blk = blockIdx.x;
  const int l15 = lane & 15, lq = lane >> 4;
  const int m = tid >> 2, dr = tid & 3;
  const int dim = blk * 4 + dr;
  const int dl = wsI[64 + m];
  const u16* W = flags[0] ? Whh16c : (const u16*)Whh;

  // ---- prologue: initial cell (h=c=0) for this thread's (m, dim) ----
  float c1, h1;
  {
    const float* gx0 = gatesx + (size_t)m * 4096 + dim;
    const float iv = gx0[0], gv = gx0[2048], ov = gx0[3072];
    c1 = sigf(iv) * tanhf_(gv);             // f*c vanishes (c=0)
    h1 = sigf(ov) * tanhf_(c1);
  }
  hl[m * 4 + dr] = h1;
  // ---- W_hh fragments resident: B-row = l15 -> (gate l15>>2, dim blk*4+(l15&3)) ----
  const int brow = (l15 >> 2) * 1024 + blk * 4 + (l15 & 3);
  us8 breg[8];
  {
    const u16* Bp = W + (size_t)brow * 1024 + wave * 256 + lq * 8;
#pragma unroll
    for(int kt = 0; kt < 8; ++kt) breg[kt] = *(const us8*)(Bp + kt * 32);
  }
  __syncthreads();
  if(tid < 64) stH(Hbuf + (size_t)tid * 1024 + blk * 4, pack4bf(&hl[tid * 4]));
  gbar(flagv, 1u, tid, blk);                // H(0) at L3, all blocks arrived

#pragma unroll 1
  for(int t = 0; t < 31; ++t){
    // ---- hoisted gatesx loads for this step's finish (independent of H) ----
    const float* gx = gatesx + ((size_t)(t + 1) * 64 + m) * 4096 + dim;
    float gpre[4];
#pragma unroll
    for(int g = 0; g < 4; ++g) gpre[g] = gx[(size_t)g * 1024];
    // ---- prefetch ALL 32 H fragments (one exposed L3 latency), then MFMA ----
    const u16* Ht = Hbuf + (size_t)t * 65536 + wave * 256 + lq * 8;
    us8 af[32];
#pragma unroll
    for(int kt = 0; kt < 8; ++kt)
#pragma unroll
      for(int mi = 0; mi < 4; ++mi)
        af[kt * 4 + mi] = ldH8(Ht + (size_t)(mi * 16 + l15) * 1024 + kt * 32);
    f32x4 acc[4] = {};
#pragma unroll
    for(int kt = 0; kt < 8; ++kt)
#pragma unroll
      for(int mi = 0; mi < 4; ++mi)
        acc[mi] = mfma16(af[kt * 4 + mi], breg[kt], acc[mi]);
    // ---- cross-wave K-reduce via LDS ----
#pragma unroll
    for(int mi = 0; mi < 4; ++mi)
#pragma unroll
      for(int v = 0; v < 4; ++v)
        red[wave * 1024 + (mi * 16 + lq * 4 + v) * 16 + l15] = acc[mi][v];
    __syncthreads();
    // ---- per-thread (m, dim) gate finish ----
    float g4[4];
#pragma unroll
    for(int g = 0; g < 4; ++g){
      const int n = g * 4 + dr;
      g4[g] = red[m * 16 + n] + red[1024 + m * 16 + n]
            + red[2048 + m * 16 + n] + red[3072 + m * 16 + n]
            + gpre[g];
    }
    if(t < dl){
      const float cn = sigf(g4[1]) * c1 + sigf(g4[0]) * tanhf_(g4[2]);
      c1 = cn;
      h1 = sigf(g4[3]) * tanhf_(cn);
    }
    hl[m * 4 + dr] = h1;
    __syncthreads();
    if(tid < 64) stH(Hbuf + ((size_t)(t + 1) * 64 + tid) * 1024 + blk * 4, pack4bf(&hl[tid * 4]));
    if(t < 30) gbar(flagv, (unsigned)(t + 2), tid, blk);   // kernel boundary covers t=30
  }
}

// ---------------- K6: preds = H @ fc_W^T + fc_b, masked; coalesced LDS epilogue ----------------
__global__ void __launch_bounds__(256) k_gemm_fc(const u16* __restrict__ H,
    const void* __restrict__ fcW, const u16* __restrict__ fcW16, const int useW16,
    const void* __restrict__ fcb, const int* __restrict__ declen,
    const int* __restrict__ flags, void* __restrict__ out){
  __shared__ u16 smem[8192];                // mainloop: As|Bs; epilogue: 32x128 stage
  u16* As = smem; u16* Bs = smem + 4096;
  const int tid = threadIdx.x, wave = tid >> 6, lane = tid & 63;
  const int bid = blockIdx.x;
  const int L = (bid & 7) * 500 + (bid >> 3);    // XCD-chunked bijective swizzle
  const int bm = L & 15, bn = L >> 4;            // bm innermost: B-strip L2-resident
  const int mq = (wave >> 1) * 64, nq = (wave & 1) * 64;
  const int l15 = lane & 15, lq = lane >> 4;
  const int f32 = flags[0];
  const void* Bbase; int bf32;
  if(f32){
    if(useW16){ Bbase = fcW16 + (size_t)bn * 131072; bf32 = 0; }
    else      { Bbase = (const float*)fcW + (size_t)bn * 131072; bf32 = 1; }
  } else      { Bbase = (const u16*)fcW + (size_t)bn * 131072; bf32 = 0; }  // already bf16
  f32x4 acc[4][4] = {};
  const int amax0 = 1983 - bm * 128;
  gemm_main(H + (size_t)bm * 131072, Bbase, bf32, amax0 > 127 ? 127 : amax0, As, Bs, acc);
  float bias[4];
#pragma unroll
  for(int j = 0; j < 4; ++j) bias[j] = ldf(fcb, f32, bn * 128 + nq + j * 16 + l15);
  __syncthreads();
  // 4 chunks of 32 rows x 128 cols: stage (masked) -> coalesced 16B stores
  for(int i = 0; i < 4; ++i){
#pragma unroll
    for(int v = 0; v < 4; ++v){
      const int row = bm * 128 + mq + i * 16 + lq * 4 + v;
      const int s = (wave >> 1) * 16 + lq * 4 + v;       // staged row 0..31
      bool act = false;
      if(row < 1984) act = ((row >> 6) < declen[row & 63]);
#pragma unroll
      for(int j = 0; j < 4; ++j){
        const float val = act ? (acc[i][j][v] + bias[j]) : 0.f;
        const int cl = nq + j * 16 + l15;
        if(f32) ((float*)smem)[s * 128 + cl] = val;      // 16KB (As+Bs)
        else    smem[s * 128 + cl] = f2bf(val);          // 8KB
      }
    }
    __syncthreads();
    if(f32){
#pragma unroll
      for(int p = 0; p < 4; ++p){
        const int idx = p * 256 + tid;
        const int s = idx >> 5, c = (idx & 31) * 4;
        const int grow = bm * 128 + (s >> 4) * 64 + i * 16 + (s & 15);
        if(grow < 1984){
          const int tt = grow >> 6, b = grow & 63;
          *(float4*)((float*)out + (size_t)b * 992000 + (size_t)tt * 32000 + bn * 128 + c)
              = *(const float4*)((const float*)smem + s * 128 + c);
        }
      }
    } else {
#pragma unroll
      for(int p = 0; p < 2; ++p){
        const int idx = p * 256 + tid;
        const int s = idx >> 4, c = (idx & 15) * 8;
        const int grow = bm * 128 + (s >> 4) * 64 + i * 16 + (s & 15);
        if(grow < 1984){
          const int tt = grow >> 6, b = grow & 63;
          *(us8*)((u16*)out + (size_t)b * 992000 + (size_t)tt * 32000 + bn * 128 + c)
              = *(const us8*)(smem + s * 128 + c);
        }
      }
    }
    __syncthreads();
  }
}

extern "C" void kernel_launch(void* const* d_in, const int* in_sizes, int n_in,
                              void* d_out, int out_size, void* d_ws, size_t ws_size,
                              hipStream_t stream){
  const void* enc = d_in[0];
  const int*  caps = (const int*)d_in[1];
  const int*  lens = (const int*)d_in[2];
  const void* emb = d_in[3];
  const void* Wih = d_in[4];
  const void* Whh = d_in[5];
  const void* bih = d_in[6];
  const void* bhh = d_in[7];
  const void* fcW = d_in[8];
  const void* fcb = d_in[9];

  // Big scratch in d_out's preds region (dead until k_gemm_fc overwrites it):
  float* gatesx = (float*)d_out;                                   // 32 MB fp32 @ +0
  u16*   Xbuf   = (u16*)((char*)d_out + (size_t)32*1024*1024);     // 4 MB bf16 @ +32MB
  u16*   Whh16  = (u16*)((char*)d_out + (size_t)36*1024*1024);     // 8 MB bf16 @ +36MB
  u16*   Wih16  = (u16*)((char*)d_out + (size_t)36*1024*1024 + 8388608); // 8 MB bf16
  // Small persistent scratch in d_ws:
  char* ws = (char*)d_ws;
  int*      flags = (int*)ws;                                      // [0]=fp32?, [1]=int64?
  int*      wsI   = (int*)(ws + 256);                              // [0..63] sort_ind, [64..127] declen
  unsigned* flagv = (unsigned*)(ws + 4096);                        // 256-entry barrier flags
  u16*      Hbuf  = (u16*)(ws + (size_t)512*1024);                 // 2048x1024 bf16 = 4 MB
  u16*      fcW16 = (u16*)(ws + (size_t)8*1024*1024);              // 65.5 MB bf16 (optional)
  const int useFc16 = (ws_size >= (size_t)74*1024*1024) ? 1 : 0;

  hipLaunchKernelGGL(k_detect, dim3(1), dim3(64), 0, stream,
                     (const unsigned*)emb, lens, flags);
  hipLaunchKernelGGL(k_setup, dim3(1), dim3(64), 0, stream, lens, wsI, flags, d_out);
  hipLaunchKernelGGL(k_conv16, dim3(2048), dim3(256), 0, stream, Wih, flags, Wih16, 524288);
  hipLaunchKernelGGL(k_conv16, dim3(2048), dim3(256), 0, stream, Whh, flags, Whh16, 524288);
  if(useFc16)
    hipLaunchKernelGGL(k_conv16, dim3(4096), dim3(256), 0, stream, fcW, flags, fcW16, 4096000);
  hipLaunchKernelGGL(k_gather, dim3(2048), dim3(256), 0, stream, enc, caps, emb, wsI, flags, Xbuf);
  hipLaunchKernelGGL(k_gemm_gates, dim3(16, 32), dim3(256), 0, stream,
                     Xbuf, Wih, Wih16, bih, bhh, flags, gatesx);

  {
    const void* a0 = Whh; const u16* a1 = Whh16; const float* a2 = gatesx;
    const int* a3 = wsI; const int* a4 = flags; u16* a5 = Hbuf; unsigned* a6 = flagv;
    void* kargs[] = {(void*)&a0, (void*)&a1, (void*)&a2, (void*)&a3,
                     (void*)&a4, (void*)&a5, (void*)&a6};
    hipLaunchCooperativeKernel((const void*)k_rnn6, dim3(256), dim3(256), kargs, 0, stream);
  }

  hipLaunchKernelGGL(k_gemm_fc, dim3(4000), dim3(256), 0, stream,
                     Hbuf + (size_t)64 * 1024, fcW, fcW16, useFc16, fcb, wsI + 64, flags, d_out);
}